// Round 15
// baseline (374.882 us; speedup 1.0000x reference)
//
#include <hip/hip_runtime.h>
#include <math.h>

#define MM 100     // mentions
#define CC 30      // candidates
#define DE 300     // embedding dim
#define NK 3       // relation types
#define NLOOP 10   // LBP iterations
#define INV_SQRT_D 0.05773502691896258f   // 1/sqrt(300)

typedef __attribute__((ext_vector_type(8))) short bf16x8;
typedef __attribute__((ext_vector_type(4))) float f32x4;

// ws layout (floats):
//  f@0 psi@60000 t@63000 a@153000
//  REH@183000 REL@1719000 (bf16 [k][i][32][320] padded hi/lo)
//  entH@3255000 entL@3767000 (bf16 [j][32][320])
//  phi@4279000 (fp16 [i][j][30][30] = 4.5M floats worth)
//  mbarA@13279000 mbarB@13579000 stotbuf@13879000 (11*3000)
//  RH/RL: transient at phi start; g stash: transient at ws+183000

__device__ inline void bf16split(float x, short* hi, short* lo) {
  unsigned u  = __float_as_uint(x);
  unsigned hu = u & 0xFFFF0000u;
  float xh = __uint_as_float(hu);
  float rl = x - xh;
  unsigned lu = __float_as_uint(rl);
  lu += 0x7FFFu + ((lu >> 16) & 1u);
  *hi = (short)(hu >> 16);
  *lo = (short)(lu >> 16);
}

// ---------- f[m,:] = tanh(fmc[m,:] @ W + b): 1 block/m, no atomics ----------
__global__ __launch_bounds__(320) void k_f(const float* __restrict__ fmc,
                                           const float* __restrict__ W,
                                           const float* __restrict__ b,
                                           float* __restrict__ f) {
  __shared__ float xs[3*DE];
  const int m = blockIdx.x;
  for (int e = threadIdx.x; e < 3*DE; e += 320) xs[e] = fmc[m*3*DE + e];
  __syncthreads();
  const int d = threadIdx.x;
  if (d < DE) {
    float a0 = b[d], a1 = 0.f;
    for (int e = 0; e < 3*DE; e += 2) {
      a0 = fmaf(xs[e],     W[e*DE + d],       a0);
      a1 = fmaf(xs[e + 1], W[(e + 1)*DE + d], a1);
    }
    f[m*DE + d] = tanhf(a0 + a1);
  }
}

// ---------- g & t: wave-per-dot over stacked [B; D] rows, 1900 blocks ----------
__global__ __launch_bounds__(256) void k_gt(const float* __restrict__ Bm,
                                            const float* __restrict__ Dm,
                                            const float* __restrict__ f,
                                            float* __restrict__ gst,
                                            float* __restrict__ t) {
  __shared__ float fs[DE];
  const int m  = blockIdx.x / 19;
  const int cg = blockIdx.x % 19;
  const int wave = threadIdx.x >> 6, lane = threadIdx.x & 63;
  for (int e = threadIdx.x; e < DE; e += 256) fs[e] = f[m*DE + e];
  __syncthreads();

  #pragma unroll
  for (int u = 0; u < 16; ++u) {
    const int col = cg*64 + wave*16 + u;
    const bool ok = (col < 1200);
    const int ccl = ok ? col : 0;
    const float* row = (ccl < DE) ? (Bm + ccl*DE) : (Dm + (ccl - DE)*DE);
    float acc = 0.f;
    for (int e = lane; e < DE; e += 64) acc = fmaf(row[e], fs[e], acc);
    #pragma unroll
    for (int off = 32; off; off >>= 1) acc += __shfl_down(acc, off, 64);
    if (ok && lane == 0) {
      if (col < DE) {
        gst[m*DE + col] = acc;
      } else {
        const int k = (col - DE) / DE, d = (col - DE) % DE;
        t[(k*MM + m)*DE + d] = acc;
      }
    }
  }
}

// ---------- fused aux: a2(2500) + psi2(800) + esplit(400) + Rsplit(120) + zero(248) ----------
__global__ __launch_bounds__(256) void k_aux(const float* __restrict__ ent,
                                             const float* __restrict__ f,
                                             const float* __restrict__ gst,
                                             const float* __restrict__ t,
                                             const float* __restrict__ R,
                                             float* __restrict__ psi,
                                             float* __restrict__ a,
                                             short* __restrict__ entH,
                                             short* __restrict__ entL,
                                             short* __restrict__ RH,
                                             short* __restrict__ RL,
                                             float* __restrict__ zbase) {
  __shared__ float sh[DE];
  const int bs = blockIdx.x;
  const int wave = threadIdx.x >> 6, lane = threadIdx.x & 63;

  if (bs < 2500) {
    // ---- a[i,j,:] = softmax_k( f_i · t[k,j,:] / sqrt(D) ) ----
    const int i  = bs / 25;
    const int jg = bs % 25;
    for (int e = threadIdx.x; e < DE; e += 256) sh[e] = f[i*DE + e];
    __syncthreads();
    const int j = jg*4 + wave;
    float sk[NK];
    #pragma unroll
    for (int k = 0; k < NK; ++k) {
      float acc = 0.f;
      const float* tr = t + (k*MM + j)*DE;
      for (int d = lane; d < DE; d += 64) acc = fmaf(sh[d], tr[d], acc);
      #pragma unroll
      for (int off = 32; off; off >>= 1) acc += __shfl_down(acc, off, 64);
      sk[k] = acc;
    }
    if (lane == 0) {
      float s0 = sk[0]*INV_SQRT_D, s1 = sk[1]*INV_SQRT_D, s2 = sk[2]*INV_SQRT_D;
      float mx = fmaxf(s0, fmaxf(s1, s2));
      float e0 = expf(s0 - mx), e1 = expf(s1 - mx), e2 = expf(s2 - mx);
      float inv = 1.f / (e0 + e1 + e2);
      float* ar = a + (i*MM + j)*NK;
      ar[0] = e0*inv; ar[1] = e1*inv; ar[2] = e2*inv;
    }
  } else if (bs < 3300) {
    // ---- psi[m,c] = ent[m,c,:] · g[m,:] ----
    const int bb = bs - 2500;
    const int m  = bb >> 3;
    const int cg = bb & 7;
    for (int e = threadIdx.x; e < DE; e += 256) sh[e] = gst[m*DE + e];
    __syncthreads();
    const int c = cg*4 + wave;
    if (c < CC) {
      float acc = 0.f;
      const float* er = ent + (m*CC + c)*DE;
      for (int d = lane; d < DE; d += 64) acc = fmaf(er[d], sh[d], acc);
      #pragma unroll
      for (int off = 32; off; off >>= 1) acc += __shfl_down(acc, off, 64);
      if (lane == 0) psi[m*CC + c] = acc;
    }
  } else if (bs < 3700) {
    // ---- split ent -> padded bf16 hi/lo [j][32][320] ----
    const int r = bs - 3300;          // 0..399
    const int j = r >> 2;
    const int base = (r & 3) * 2560;
    for (int off = 0; off < 2560; off += 256) {
      int idx = base + off + threadIdx.x;
      int q = idx / 320, kk = idx % 320;
      float x = (q < CC && kk < DE) ? ent[(j*CC + q)*DE + kk] : 0.f;
      short h, l;
      bf16split(x, &h, &l);
      entH[(j*32 + q)*320 + kk] = h;
      entL[(j*32 + q)*320 + kk] = l;
    }
  } else if (bs < 3820) {
    // ---- split R -> padded bf16 hi/lo [k][320][320] ----
    const int r = bs - 3700;          // 0..119
    for (int off = 0; off < 2560; off += 256) {
      int idx = r*2560 + off + threadIdx.x;   // 0..307199
      int k   = idx / (320*320);
      int rem = idx % (320*320);
      int d = rem / 320, e = rem % 320;
      float x = (d < DE && e < DE) ? R[(k*DE + d)*DE + e] : 0.f;
      short h, l;
      bf16split(x, &h, &l);
      RH[idx] = h;
      RL[idx] = l;
    }
  } else {
    // ---- zero mbA/mbB/stotbuf (633000 floats) ----
    const int z = bs - 3820;          // 0..247
    for (int off = 0; off < 2560; off += 256) {
      int idx = z*2560 + off + threadIdx.x;
      if (idx < 633000) zbase[idx] = 0.f;
    }
  }
}

// ---------- RE GEMM via MFMA bf16-split (R7-verified) ----------
__global__ __launch_bounds__(256) void k_re2(const short* __restrict__ RH,
                                             const short* __restrict__ RL,
                                             const short* __restrict__ entH,
                                             const short* __restrict__ entL,
                                             short* __restrict__ REH,
                                             short* __restrict__ REL) {
  const int k  = blockIdx.z;
  const int d0 = blockIdx.x * 32;
  const int m0 = blockIdx.y * 128;
  const int wave = threadIdx.x >> 6;
  const int lane = threadIdx.x & 63;
  const int row = lane & 15;
  const int g8  = (lane >> 4) << 3;

  const int rbase = m0 + wave*32;
  const short* aH = entH + (rbase + row)*320 + g8;
  const short* aL = entL + (rbase + row)*320 + g8;
  const short* bH = RH + (k*320 + d0 + row)*320 + g8;
  const short* bL = RL + (k*320 + d0 + row)*320 + g8;

  f32x4 acc[2][2];
  #pragma unroll
  for (int rb = 0; rb < 2; ++rb)
    #pragma unroll
    for (int sb = 0; sb < 2; ++sb)
      acc[rb][sb] = (f32x4){0.f, 0.f, 0.f, 0.f};

  #pragma unroll
  for (int c = 0; c < 10; ++c) {
    const int kk = c*32;
    bf16x8 AH0 = *(const bf16x8*)(aH + kk);
    bf16x8 AH1 = *(const bf16x8*)(aH + 16*320 + kk);
    bf16x8 AL0 = *(const bf16x8*)(aL + kk);
    bf16x8 AL1 = *(const bf16x8*)(aL + 16*320 + kk);
    bf16x8 BH0 = *(const bf16x8*)(bH + kk);
    bf16x8 BH1 = *(const bf16x8*)(bH + 16*320 + kk);
    bf16x8 BL0 = *(const bf16x8*)(bL + kk);
    bf16x8 BL1 = *(const bf16x8*)(bL + 16*320 + kk);

    acc[0][0] = __builtin_amdgcn_mfma_f32_16x16x32_bf16(AH0, BH0, acc[0][0], 0, 0, 0);
    acc[0][0] = __builtin_amdgcn_mfma_f32_16x16x32_bf16(AH0, BL0, acc[0][0], 0, 0, 0);
    acc[0][0] = __builtin_amdgcn_mfma_f32_16x16x32_bf16(AL0, BH0, acc[0][0], 0, 0, 0);
    acc[0][1] = __builtin_amdgcn_mfma_f32_16x16x32_bf16(AH0, BH1, acc[0][1], 0, 0, 0);
    acc[0][1] = __builtin_amdgcn_mfma_f32_16x16x32_bf16(AH0, BL1, acc[0][1], 0, 0, 0);
    acc[0][1] = __builtin_amdgcn_mfma_f32_16x16x32_bf16(AL0, BH1, acc[0][1], 0, 0, 0);
    acc[1][0] = __builtin_amdgcn_mfma_f32_16x16x32_bf16(AH1, BH0, acc[1][0], 0, 0, 0);
    acc[1][0] = __builtin_amdgcn_mfma_f32_16x16x32_bf16(AH1, BL0, acc[1][0], 0, 0, 0);
    acc[1][0] = __builtin_amdgcn_mfma_f32_16x16x32_bf16(AL1, BH0, acc[1][0], 0, 0, 0);
    acc[1][1] = __builtin_amdgcn_mfma_f32_16x16x32_bf16(AH1, BH1, acc[1][1], 0, 0, 0);
    acc[1][1] = __builtin_amdgcn_mfma_f32_16x16x32_bf16(AH1, BL1, acc[1][1], 0, 0, 0);
    acc[1][1] = __builtin_amdgcn_mfma_f32_16x16x32_bf16(AL1, BH1, acc[1][1], 0, 0, 0);
  }

  const int rb4 = (lane >> 4) * 4;
  #pragma unroll
  for (int rb = 0; rb < 2; ++rb) {
    #pragma unroll
    for (int t = 0; t < 4; ++t) {
      const int rp = rbase + rb*16 + rb4 + t;
      const int i = rp >> 5, p = rp & 31;
      #pragma unroll
      for (int sb = 0; sb < 2; ++sb) {
        const int d = d0 + sb*16 + row;
        size_t idx = (((size_t)k*MM + i)*32 + p)*320 + d;
        short h, l;
        bf16split(acc[rb][sb][t], &h, &l);
        REH[idx] = h;
        REL[idx] = l;
      }
    }
  }
}

// ---------- phi via MFMA: 2-chunk LDS stages (R10-verified), fp16 phi output ----------
__global__ __launch_bounds__(256) void k_phi10(const float* __restrict__ a,
                                               const short* __restrict__ REH,
                                               const short* __restrict__ REL,
                                               const short* __restrict__ entH,
                                               const short* __restrict__ entL,
                                               _Float16* __restrict__ phi) {
  __shared__ short As[2][12][2][512];   // 49,152 B
  const int bs = blockIdx.x;
  int i, jg;
  if (bs < 2400) {
    int x = bs & 7;
    int s = bs >> 3;
    jg = s / 12;
    i  = x*12 + s % 12;
  } else {
    int r = bs - 2400;
    i  = 96 + (r & 3);
    jg = r >> 2;
  }
  const int wave = threadIdx.x >> 6;
  const int lane = threadIdx.x & 63;
  const int j = jg*4 + wave;

  const int row = lane & 15;
  const int g8  = (lane >> 4) << 3;

  const float a0 = a[(i*MM + j)*NK + 0];
  const float a1 = a[(i*MM + j)*NK + 1];
  const float a2 = a[(i*MM + j)*NK + 2];

  const int b0 = (j*32 + row)*320 + g8;
  const int b1 = b0 + 16*320;

  const short* asrc[3];
  int frr[3];
  #pragma unroll
  for (int q = 0; q < 3; ++q) {
    const int fr = 3*wave + q;
    const int b6 = fr % 6;
    const int kr = b6 >> 1, rb = b6 & 1;
    const short* src = (fr < 6) ? REH : REL;
    asrc[q] = src + ((kr*MM + i)*32 + rb*16 + row)*320 + g8;
    frr[q] = fr;
  }

  f32x4 acc[3][2][2];
  #pragma unroll
  for (int kr = 0; kr < 3; ++kr)
    #pragma unroll
    for (int r = 0; r < 2; ++r)
      #pragma unroll
      for (int s = 0; s < 2; ++s)
        acc[kr][r][s] = (f32x4){0.f, 0.f, 0.f, 0.f};

  #pragma unroll
  for (int q = 0; q < 3; ++q) {
    int4 v0 = *(const int4*)(asrc[q]);
    int4 v1 = *(const int4*)(asrc[q] + 32);
    *(int4*)(&As[0][frr[q]][0][lane*8]) = v0;
    *(int4*)(&As[0][frr[q]][1][lane*8]) = v1;
  }
  __syncthreads();

  int cur = 0;
  for (int s = 0; s < 5; ++s) {
    int4 pv0[3], pv1[3];
    if (s < 4) {
      #pragma unroll
      for (int q = 0; q < 3; ++q) {
        pv0[q] = *(const int4*)(asrc[q] + ((s+1)*2 + 0)*32);
        pv1[q] = *(const int4*)(asrc[q] + ((s+1)*2 + 1)*32);
      }
    }

    #pragma unroll
    for (int cc = 0; cc < 2; ++cc) {
      const int kk = (s*2 + cc)*32;
      bf16x8 BH0 = *(const bf16x8*)(entH + b0 + kk);
      bf16x8 BH1 = *(const bf16x8*)(entH + b1 + kk);
      bf16x8 BL0 = *(const bf16x8*)(entL + b0 + kk);
      bf16x8 BL1 = *(const bf16x8*)(entL + b1 + kk);

      #pragma unroll
      for (int kr = 0; kr < 3; ++kr) {
        bf16x8 AH0 = *(const bf16x8*)(&As[cur][kr*2 + 0][cc][lane*8]);
        bf16x8 AH1 = *(const bf16x8*)(&As[cur][kr*2 + 1][cc][lane*8]);
        bf16x8 AL0 = *(const bf16x8*)(&As[cur][6 + kr*2 + 0][cc][lane*8]);
        bf16x8 AL1 = *(const bf16x8*)(&As[cur][6 + kr*2 + 1][cc][lane*8]);
        acc[kr][0][0] = __builtin_amdgcn_mfma_f32_16x16x32_bf16(AH0, BH0, acc[kr][0][0], 0, 0, 0);
        acc[kr][0][0] = __builtin_amdgcn_mfma_f32_16x16x32_bf16(AH0, BL0, acc[kr][0][0], 0, 0, 0);
        acc[kr][0][0] = __builtin_amdgcn_mfma_f32_16x16x32_bf16(AL0, BH0, acc[kr][0][0], 0, 0, 0);
        acc[kr][0][1] = __builtin_amdgcn_mfma_f32_16x16x32_bf16(AH0, BH1, acc[kr][0][1], 0, 0, 0);
        acc[kr][0][1] = __builtin_amdgcn_mfma_f32_16x16x32_bf16(AH0, BL1, acc[kr][0][1], 0, 0, 0);
        acc[kr][0][1] = __builtin_amdgcn_mfma_f32_16x16x32_bf16(AL0, BH1, acc[kr][0][1], 0, 0, 0);
        acc[kr][1][0] = __builtin_amdgcn_mfma_f32_16x16x32_bf16(AH1, BH0, acc[kr][1][0], 0, 0, 0);
        acc[kr][1][0] = __builtin_amdgcn_mfma_f32_16x16x32_bf16(AH1, BL0, acc[kr][1][0], 0, 0, 0);
        acc[kr][1][0] = __builtin_amdgcn_mfma_f32_16x16x32_bf16(AL1, BH0, acc[kr][1][0], 0, 0, 0);
        acc[kr][1][1] = __builtin_amdgcn_mfma_f32_16x16x32_bf16(AH1, BH1, acc[kr][1][1], 0, 0, 0);
        acc[kr][1][1] = __builtin_amdgcn_mfma_f32_16x16x32_bf16(AH1, BL1, acc[kr][1][1], 0, 0, 0);
        acc[kr][1][1] = __builtin_amdgcn_mfma_f32_16x16x32_bf16(AL1, BH1, acc[kr][1][1], 0, 0, 0);
      }
    }

    if (s < 4) {
      #pragma unroll
      for (int q = 0; q < 3; ++q) {
        *(int4*)(&As[cur^1][frr[q]][0][lane*8]) = pv0[q];
        *(int4*)(&As[cur^1][frr[q]][1][lane*8]) = pv1[q];
      }
      __syncthreads();
      cur ^= 1;
    }
  }

  _Float16* ph = phi + (size_t)(i*MM + j)*CC*CC;
  const int rbase = (lane >> 4) * 4;
  #pragma unroll
  for (int r = 0; r < 2; ++r) {
    #pragma unroll
    for (int t = 0; t < 4; ++t) {
      const int p = 16*r + rbase + t;
      if (p < CC) {
        #pragma unroll
        for (int s = 0; s < 2; ++s) {
          const int q = 16*s + row;
          if (q < CC) {
            float v = a0*acc[0][r][s][t] + a1*acc[1][r][s][t] + a2*acc[2][r][s][t];
            ph[p*CC + q] = (_Float16)v;
          }
        }
      }
    }
  }
}

// ---------- damped LBP update + fused stot, XCD-swizzled, fp16 phi ----------
__global__ __launch_bounds__(256) void k_up4(const _Float16* __restrict__ phi,
                                             const float* __restrict__ psi,
                                             const float* __restrict__ stot_cur,
                                             float* __restrict__ stot_next,
                                             const float* __restrict__ mb_old,
                                             float* __restrict__ mb_new) {
  // nwg = 2500, NXCD = 8: q8 = 312, r8 = 4
  const int orig = blockIdx.x;
  const int xcd  = orig & 7;
  const int pos  = orig >> 3;
  const int wgid = (xcd < 4) ? xcd*313 + pos : 4*313 + (xcd - 4)*312 + pos;

  const int i  = wgid / 25;
  const int jg = wgid % 25;
  const int wave = threadIdx.x >> 6;
  const int lane = threadIdx.x & 63;
  const int j = jg*4 + wave;
  const int half = lane >> 5;
  const int q = lane & 31;

  __shared__ float psi_st[32];
  if (threadIdx.x < CC)
    psi_st[threadIdx.x] = psi[i*CC + threadIdx.x] + stot_cur[i*CC + threadIdx.x];
  __syncthreads();

  float csr = (q < CC) ? psi_st[q] - mb_old[(j*MM + i)*CC + q] : -1e30f;

  const _Float16* ph = phi + (size_t)(i*MM + j)*CC*CC;
  float mv = -1e30f;
  const int p0 = half * 15;
  #pragma unroll
  for (int pp = 0; pp < 15; ++pp) {
    const int p = p0 + pp;
    float v = (q < CC) ? (float)ph[p*CC + q] : -1e30f;
    float cv = __shfl(csr, p, 64);
    mv = fmaxf(mv, v + cv);
  }
  mv = fmaxf(mv, __shfl_xor(mv, 32, 64));
  float x = (q < CC) ? fmaxf(mv, 0.f) : -1e30f;

  float mx = x;
  #pragma unroll
  for (int off = 16; off; off >>= 1) mx = fmaxf(mx, __shfl_xor(mx, off, 64));
  float e = (q < CC) ? expf(x - mx) : 0.f;
  float se = e;
  #pragma unroll
  for (int off = 16; off; off >>= 1) se += __shfl_xor(se, off, 64);

  if (lane < CC) {
    float sm = e / se;
    float old = mb_old[(i*MM + j)*CC + lane];
    float nv = logf(0.5f*expf(old) + 0.5f*sm);
    mb_new[(i*MM + j)*CC + lane] = nv;
    atomicAdd(stot_next + j*CC + lane, nv);
  }
}

// ---------- out[i,:] = softmax( psi + stot_final[i,:] - mbar[i,i,:] ) ----------
__global__ __launch_bounds__(64) void k_final(const float* __restrict__ psi,
                                              const float* __restrict__ stotN,
                                              const float* __restrict__ mb,
                                              float* __restrict__ out) {
  int i = blockIdx.x;
  int lane = threadIdx.x;
  float x = -1e30f;
  if (lane < CC)
    x = psi[i*CC + lane] + stotN[i*CC + lane] - mb[(i*MM + i)*CC + lane];
  float mx = x;
  #pragma unroll
  for (int off = 16; off; off >>= 1) mx = fmaxf(mx, __shfl_xor(mx, off, 32));
  float e = (lane < CC) ? expf(x - mx) : 0.f;
  float se = e;
  #pragma unroll
  for (int off = 16; off; off >>= 1) se += __shfl_xor(se, off, 32);
  if (lane < CC) out[i*CC + lane] = e / se;
}

extern "C" void kernel_launch(void* const* d_in, const int* in_sizes, int n_in,
                              void* d_out, int out_size, void* d_ws, size_t ws_size,
                              hipStream_t stream) {
  (void)in_sizes; (void)n_in; (void)out_size; (void)ws_size;
  const float* ent  = (const float*)d_in[0];
  const float* fmc  = (const float*)d_in[1];
  const float* W    = (const float*)d_in[2];
  const float* b    = (const float*)d_in[3];
  const float* Bm   = (const float*)d_in[4];
  const float* R    = (const float*)d_in[5];
  const float* Dm   = (const float*)d_in[6];
  float* out = (float*)d_out;
  float* ws  = (float*)d_ws;

  float* f    = ws + 0;
  float* psi  = ws + 60000;
  float* t    = ws + 63000;
  float* a    = ws + 153000;
  short* REH  = (short*)(ws + 183000);
  short* REL  = (short*)(ws + 1719000);
  short* entH = (short*)(ws + 3255000);
  short* entL = (short*)(ws + 3767000);
  _Float16* phi = (_Float16*)(ws + 4279000);   // fp16 [10000][900]
  float* mbA  = ws + 13279000;
  float* mbB  = ws + 13579000;
  float* stotbuf = ws + 13879000;   // (NLOOP+1)*3000 floats
  float* gst  = ws + 183000;        // transient g stash (REH area, consumed before k_re2)
  short* RH   = (short*)phi;        // transient R split (phi area, dead before k_phi10)
  short* RL   = RH + NK*320*320;

  k_f  <<<MM, 320, 0, stream>>>(fmc, W, b, f);
  k_gt <<<1900, 256, 0, stream>>>(Bm, Dm, f, gst, t);
  k_aux<<<4068, 256, 0, stream>>>(ent, f, gst, t, R, psi, a, entH, entL, RH, RL, mbA);

  {
    dim3 grid(10, 25, 3);
    k_re2<<<grid, 256, 0, stream>>>(RH, RL, entH, entL, REH, REL);
  }
  k_phi10<<<2500, 256, 0, stream>>>(a, REH, REL, entH, entL, phi);

  float* cur = mbA; float* nxt = mbB;
  for (int it = 0; it < NLOOP; ++it) {
    k_up4<<<MM*25, 256, 0, stream>>>(phi, psi,
                                     stotbuf + it*MM*CC,
                                     stotbuf + (it+1)*MM*CC,
                                     cur, nxt);
    float* tmp = cur; cur = nxt; nxt = tmp;
  }
  k_final<<<MM, 64, 0, stream>>>(psi, stotbuf + NLOOP*MM*CC, cur, out);
}

// Round 16
// 364.858 us; speedup vs baseline: 1.0275x; 1.0275x over previous
//
#include <hip/hip_runtime.h>
#include <math.h>

#define MM 100     // mentions
#define CC 30      // candidates
#define DE 300     // embedding dim
#define NK 3       // relation types
#define NLOOP 10   // LBP iterations
#define INV_SQRT_D 0.05773502691896258f   // 1/sqrt(300)

typedef __attribute__((ext_vector_type(8))) short bf16x8;
typedef __attribute__((ext_vector_type(4))) float f32x4;

// ws layout (floats):
//  f@0 psi@60000 t@63000 a@153000
//  REH@183000 REL@1719000 (bf16 [k][i][32][320] padded hi/lo)
//  entH@3255000 entL@3767000 (bf16 [j][32][320])
//  phi@4279000  mbarA@13279000 mbarB@13579000 stotbuf@13879000 (11*3000)
//  RH/RL: transient at phi start (bf16 [k][320][320] each; dead before k_phi7 writes phi)
//  g stash: transient at ws+183000 (REH area; consumed by k_aux/psi before k_re2)

__device__ inline void bf16split(float x, short* hi, short* lo) {
  unsigned u  = __float_as_uint(x);
  unsigned hu = u & 0xFFFF0000u;
  float xh = __uint_as_float(hu);
  float rl = x - xh;
  unsigned lu = __float_as_uint(rl);
  lu += 0x7FFFu + ((lu >> 16) & 1u);
  *hi = (short)(hu >> 16);
  *lo = (short)(lu >> 16);
}

// ---------- f[m,:] = tanh(fmc[m,:] @ W + b): 1 block/m, no atomics ----------
__global__ __launch_bounds__(320) void k_f(const float* __restrict__ fmc,
                                           const float* __restrict__ W,
                                           const float* __restrict__ b,
                                           float* __restrict__ f) {
  __shared__ float xs[3*DE];
  const int m = blockIdx.x;
  for (int e = threadIdx.x; e < 3*DE; e += 320) xs[e] = fmc[m*3*DE + e];
  __syncthreads();
  const int d = threadIdx.x;
  if (d < DE) {
    float a0 = b[d], a1 = 0.f;
    for (int e = 0; e < 3*DE; e += 2) {
      a0 = fmaf(xs[e],     W[e*DE + d],       a0);
      a1 = fmaf(xs[e + 1], W[(e + 1)*DE + d], a1);
    }
    f[m*DE + d] = tanhf(a0 + a1);
  }
}

// ---------- g & t: wave-per-dot over stacked [B; D] rows, 1900 blocks ----------
__global__ __launch_bounds__(256) void k_gt(const float* __restrict__ Bm,
                                            const float* __restrict__ Dm,
                                            const float* __restrict__ f,
                                            float* __restrict__ gst,
                                            float* __restrict__ t) {
  __shared__ float fs[DE];
  const int m  = blockIdx.x / 19;
  const int cg = blockIdx.x % 19;
  const int wave = threadIdx.x >> 6, lane = threadIdx.x & 63;
  for (int e = threadIdx.x; e < DE; e += 256) fs[e] = f[m*DE + e];
  __syncthreads();

  #pragma unroll
  for (int u = 0; u < 16; ++u) {
    const int col = cg*64 + wave*16 + u;
    const bool ok = (col < 1200);
    const int ccl = ok ? col : 0;
    const float* row = (ccl < DE) ? (Bm + ccl*DE) : (Dm + (ccl - DE)*DE);
    float acc = 0.f;
    for (int e = lane; e < DE; e += 64) acc = fmaf(row[e], fs[e], acc);
    #pragma unroll
    for (int off = 32; off; off >>= 1) acc += __shfl_down(acc, off, 64);
    if (ok && lane == 0) {
      if (col < DE) {
        gst[m*DE + col] = acc;
      } else {
        const int k = (col - DE) / DE, d = (col - DE) % DE;
        t[(k*MM + m)*DE + d] = acc;
      }
    }
  }
}

// ---------- fused aux: a2 (2500) + psi2 (800) + esplit (400) + Rsplit (120) = 3820 ----------
__global__ __launch_bounds__(256) void k_aux(const float* __restrict__ ent,
                                             const float* __restrict__ f,
                                             const float* __restrict__ gst,
                                             const float* __restrict__ t,
                                             const float* __restrict__ R,
                                             float* __restrict__ psi,
                                             float* __restrict__ a,
                                             short* __restrict__ entH,
                                             short* __restrict__ entL,
                                             short* __restrict__ RH,
                                             short* __restrict__ RL) {
  __shared__ float sh[DE];
  const int bs = blockIdx.x;
  const int wave = threadIdx.x >> 6, lane = threadIdx.x & 63;

  if (bs < 2500) {
    // ---- a[i,j,:] = softmax_k( f_i · t[k,j,:] / sqrt(D) ) ----
    const int i  = bs / 25;
    const int jg = bs % 25;
    for (int e = threadIdx.x; e < DE; e += 256) sh[e] = f[i*DE + e];
    __syncthreads();
    const int j = jg*4 + wave;
    float sk[NK];
    #pragma unroll
    for (int k = 0; k < NK; ++k) {
      float acc = 0.f;
      const float* tr = t + (k*MM + j)*DE;
      for (int d = lane; d < DE; d += 64) acc = fmaf(sh[d], tr[d], acc);
      #pragma unroll
      for (int off = 32; off; off >>= 1) acc += __shfl_down(acc, off, 64);
      sk[k] = acc;
    }
    if (lane == 0) {
      float s0 = sk[0]*INV_SQRT_D, s1 = sk[1]*INV_SQRT_D, s2 = sk[2]*INV_SQRT_D;
      float mx = fmaxf(s0, fmaxf(s1, s2));
      float e0 = expf(s0 - mx), e1 = expf(s1 - mx), e2 = expf(s2 - mx);
      float inv = 1.f / (e0 + e1 + e2);
      float* ar = a + (i*MM + j)*NK;
      ar[0] = e0*inv; ar[1] = e1*inv; ar[2] = e2*inv;
    }
  } else if (bs < 3300) {
    // ---- psi[m,c] = ent[m,c,:] · g[m,:] ----
    const int bb = bs - 2500;
    const int m  = bb >> 3;
    const int cg = bb & 7;
    for (int e = threadIdx.x; e < DE; e += 256) sh[e] = gst[m*DE + e];
    __syncthreads();
    const int c = cg*4 + wave;
    if (c < CC) {
      float acc = 0.f;
      const float* er = ent + (m*CC + c)*DE;
      for (int d = lane; d < DE; d += 64) acc = fmaf(er[d], sh[d], acc);
      #pragma unroll
      for (int off = 32; off; off >>= 1) acc += __shfl_down(acc, off, 64);
      if (lane == 0) psi[m*CC + c] = acc;
    }
  } else if (bs < 3700) {
    // ---- split ent -> padded bf16 hi/lo [j][32][320] ----
    const int r = bs - 3300;          // 0..399
    const int j = r >> 2;
    const int base = (r & 3) * 2560;
    for (int off = 0; off < 2560; off += 256) {
      int idx = base + off + threadIdx.x;
      int q = idx / 320, kk = idx % 320;
      float x = (q < CC && kk < DE) ? ent[(j*CC + q)*DE + kk] : 0.f;
      short h, l;
      bf16split(x, &h, &l);
      entH[(j*32 + q)*320 + kk] = h;
      entL[(j*32 + q)*320 + kk] = l;
    }
  } else {
    // ---- split R -> padded bf16 hi/lo [k][320][320] ----
    const int r = bs - 3700;          // 0..119
    for (int off = 0; off < 2560; off += 256) {
      int idx = r*2560 + off + threadIdx.x;   // 0..307199
      int k   = idx / (320*320);
      int rem = idx % (320*320);
      int d = rem / 320, e = rem % 320;
      float x = (d < DE && e < DE) ? R[(k*DE + d)*DE + e] : 0.f;
      short h, l;
      bf16split(x, &h, &l);
      RH[idx] = h;
      RL[idx] = l;
    }
  }
}

// ---------- RE GEMM via MFMA bf16-split: RE[k][row][d] = sum_e ent[row][e]*R[k][d][e] ----------
__global__ __launch_bounds__(256) void k_re2(const short* __restrict__ RH,
                                             const short* __restrict__ RL,
                                             const short* __restrict__ entH,
                                             const short* __restrict__ entL,
                                             short* __restrict__ REH,
                                             short* __restrict__ REL) {
  const int k  = blockIdx.z;
  const int d0 = blockIdx.x * 32;
  const int m0 = blockIdx.y * 128;
  const int wave = threadIdx.x >> 6;
  const int lane = threadIdx.x & 63;
  const int row = lane & 15;
  const int g8  = (lane >> 4) << 3;

  const int rbase = m0 + wave*32;
  const short* aH = entH + (rbase + row)*320 + g8;
  const short* aL = entL + (rbase + row)*320 + g8;
  const short* bH = RH + (k*320 + d0 + row)*320 + g8;
  const short* bL = RL + (k*320 + d0 + row)*320 + g8;

  f32x4 acc[2][2];
  #pragma unroll
  for (int rb = 0; rb < 2; ++rb)
    #pragma unroll
    for (int sb = 0; sb < 2; ++sb)
      acc[rb][sb] = (f32x4){0.f, 0.f, 0.f, 0.f};

  #pragma unroll
  for (int c = 0; c < 10; ++c) {
    const int kk = c*32;
    bf16x8 AH0 = *(const bf16x8*)(aH + kk);
    bf16x8 AH1 = *(const bf16x8*)(aH + 16*320 + kk);
    bf16x8 AL0 = *(const bf16x8*)(aL + kk);
    bf16x8 AL1 = *(const bf16x8*)(aL + 16*320 + kk);
    bf16x8 BH0 = *(const bf16x8*)(bH + kk);
    bf16x8 BH1 = *(const bf16x8*)(bH + 16*320 + kk);
    bf16x8 BL0 = *(const bf16x8*)(bL + kk);
    bf16x8 BL1 = *(const bf16x8*)(bL + 16*320 + kk);

    acc[0][0] = __builtin_amdgcn_mfma_f32_16x16x32_bf16(AH0, BH0, acc[0][0], 0, 0, 0);
    acc[0][0] = __builtin_amdgcn_mfma_f32_16x16x32_bf16(AH0, BL0, acc[0][0], 0, 0, 0);
    acc[0][0] = __builtin_amdgcn_mfma_f32_16x16x32_bf16(AL0, BH0, acc[0][0], 0, 0, 0);
    acc[0][1] = __builtin_amdgcn_mfma_f32_16x16x32_bf16(AH0, BH1, acc[0][1], 0, 0, 0);
    acc[0][1] = __builtin_amdgcn_mfma_f32_16x16x32_bf16(AH0, BL1, acc[0][1], 0, 0, 0);
    acc[0][1] = __builtin_amdgcn_mfma_f32_16x16x32_bf16(AL0, BH1, acc[0][1], 0, 0, 0);
    acc[1][0] = __builtin_amdgcn_mfma_f32_16x16x32_bf16(AH1, BH0, acc[1][0], 0, 0, 0);
    acc[1][0] = __builtin_amdgcn_mfma_f32_16x16x32_bf16(AH1, BL0, acc[1][0], 0, 0, 0);
    acc[1][0] = __builtin_amdgcn_mfma_f32_16x16x32_bf16(AL1, BH0, acc[1][0], 0, 0, 0);
    acc[1][1] = __builtin_amdgcn_mfma_f32_16x16x32_bf16(AH1, BH1, acc[1][1], 0, 0, 0);
    acc[1][1] = __builtin_amdgcn_mfma_f32_16x16x32_bf16(AH1, BL1, acc[1][1], 0, 0, 0);
    acc[1][1] = __builtin_amdgcn_mfma_f32_16x16x32_bf16(AL1, BH1, acc[1][1], 0, 0, 0);
  }

  // epilogue: C[p][q] with p = (lane>>4)*4 + t (A/row side), q = lane&15 (B/d side)
  const int rb4 = (lane >> 4) * 4;
  #pragma unroll
  for (int rb = 0; rb < 2; ++rb) {
    #pragma unroll
    for (int t = 0; t < 4; ++t) {
      const int rp = rbase + rb*16 + rb4 + t;
      const int i = rp >> 5, p = rp & 31;
      #pragma unroll
      for (int sb = 0; sb < 2; ++sb) {
        const int d = d0 + sb*16 + row;
        size_t idx = (((size_t)k*MM + i)*32 + p)*320 + d;
        short h, l;
        bf16split(acc[rb][sb][t], &h, &l);
        REH[idx] = h;
        REL[idx] = l;
      }
    }
  }
}

// ---------- phi via MFMA: LDS-staged A + register-double-buffered B (R4/R7-verified) ----------
__global__ __launch_bounds__(256) void k_phi7(const float* __restrict__ a,
                                              const short* __restrict__ REH,
                                              const short* __restrict__ REL,
                                              const short* __restrict__ entH,
                                              const short* __restrict__ entL,
                                              float* __restrict__ phi) {
  __shared__ short As[2][12*512];   // 24,576 B
  const int bs = blockIdx.x;
  int i, jg;
  if (bs < 2400) {
    int x = bs & 7;
    int s = bs >> 3;
    jg = s / 12;
    i  = x*12 + s % 12;
  } else {
    int r = bs - 2400;
    i  = 96 + (r & 3);
    jg = r >> 2;
  }
  const int wave = threadIdx.x >> 6;
  const int lane = threadIdx.x & 63;
  const int j = jg*4 + wave;

  const int row = lane & 15;
  const int g8  = (lane >> 4) << 3;

  const float a0 = a[(i*MM + j)*NK + 0];
  const float a1 = a[(i*MM + j)*NK + 1];
  const float a2 = a[(i*MM + j)*NK + 2];

  const int b0 = (j*32 + row)*320;
  const int b1 = b0 + 16*320;

  const short* asrc[3];
  short* adst[3];
  #pragma unroll
  for (int q = 0; q < 3; ++q) {
    const int fr = 3*wave + q;
    const int b6 = fr % 6;
    const int kr = b6 >> 1, rb = b6 & 1;
    const short* src = (fr < 6) ? REH : REL;
    asrc[q] = src + ((kr*MM + i)*32 + rb*16 + row)*320 + g8;
    adst[q] = (short*)As + fr*512 + lane*8;
  }

  f32x4 acc[3][2][2];
  #pragma unroll
  for (int kr = 0; kr < 3; ++kr)
    #pragma unroll
    for (int r = 0; r < 2; ++r)
      #pragma unroll
      for (int s = 0; s < 2; ++s)
        acc[kr][r][s] = (f32x4){0.f, 0.f, 0.f, 0.f};

  {
    int4 v0 = *(const int4*)(asrc[0]);
    int4 v1 = *(const int4*)(asrc[1]);
    int4 v2 = *(const int4*)(asrc[2]);
    *(int4*)(adst[0]) = v0;
    *(int4*)(adst[1]) = v1;
    *(int4*)(adst[2]) = v2;
  }
  __syncthreads();

  // preload B chunk 0 into registers
  bf16x8 BH0 = *(const bf16x8*)(entH + b0 + g8);
  bf16x8 BH1 = *(const bf16x8*)(entH + b1 + g8);
  bf16x8 BL0 = *(const bf16x8*)(entL + b0 + g8);
  bf16x8 BL1 = *(const bf16x8*)(entL + b1 + g8);

  int cur = 0;
  for (int c = 0; c < 10; ++c) {
    int4 v0, v1, v2;
    bf16x8 nBH0, nBH1, nBL0, nBL1;
    if (c < 9) {
      v0 = *(const int4*)(asrc[0] + (c+1)*32);
      v1 = *(const int4*)(asrc[1] + (c+1)*32);
      v2 = *(const int4*)(asrc[2] + (c+1)*32);
      const int kk = (c+1)*32 + g8;
      nBH0 = *(const bf16x8*)(entH + b0 + kk);
      nBH1 = *(const bf16x8*)(entH + b1 + kk);
      nBL0 = *(const bf16x8*)(entL + b0 + kk);
      nBL1 = *(const bf16x8*)(entL + b1 + kk);
    }

    const short* Ab = (const short*)As + cur*12*512 + lane*8;
    #pragma unroll
    for (int kr = 0; kr < 3; ++kr) {
      bf16x8 AH0 = *(const bf16x8*)(Ab + (kr*2 + 0)*512);
      bf16x8 AH1 = *(const bf16x8*)(Ab + (kr*2 + 1)*512);
      bf16x8 AL0 = *(const bf16x8*)(Ab + (6 + kr*2 + 0)*512);
      bf16x8 AL1 = *(const bf16x8*)(Ab + (6 + kr*2 + 1)*512);
      acc[kr][0][0] = __builtin_amdgcn_mfma_f32_16x16x32_bf16(AH0, BH0, acc[kr][0][0], 0, 0, 0);
      acc[kr][0][0] = __builtin_amdgcn_mfma_f32_16x16x32_bf16(AH0, BL0, acc[kr][0][0], 0, 0, 0);
      acc[kr][0][0] = __builtin_amdgcn_mfma_f32_16x16x32_bf16(AL0, BH0, acc[kr][0][0], 0, 0, 0);
      acc[kr][0][1] = __builtin_amdgcn_mfma_f32_16x16x32_bf16(AH0, BH1, acc[kr][0][1], 0, 0, 0);
      acc[kr][0][1] = __builtin_amdgcn_mfma_f32_16x16x32_bf16(AH0, BL1, acc[kr][0][1], 0, 0, 0);
      acc[kr][0][1] = __builtin_amdgcn_mfma_f32_16x16x32_bf16(AL0, BH1, acc[kr][0][1], 0, 0, 0);
      acc[kr][1][0] = __builtin_amdgcn_mfma_f32_16x16x32_bf16(AH1, BH0, acc[kr][1][0], 0, 0, 0);
      acc[kr][1][0] = __builtin_amdgcn_mfma_f32_16x16x32_bf16(AH1, BL0, acc[kr][1][0], 0, 0, 0);
      acc[kr][1][0] = __builtin_amdgcn_mfma_f32_16x16x32_bf16(AL1, BH0, acc[kr][1][0], 0, 0, 0);
      acc[kr][1][1] = __builtin_amdgcn_mfma_f32_16x16x32_bf16(AH1, BH1, acc[kr][1][1], 0, 0, 0);
      acc[kr][1][1] = __builtin_amdgcn_mfma_f32_16x16x32_bf16(AH1, BL1, acc[kr][1][1], 0, 0, 0);
      acc[kr][1][1] = __builtin_amdgcn_mfma_f32_16x16x32_bf16(AL1, BH1, acc[kr][1][1], 0, 0, 0);
    }

    if (c < 9) {
      short* dst = (short*)As + (cur^1)*12*512;
      *(int4*)(dst + (3*wave + 0)*512 + lane*8) = v0;
      *(int4*)(dst + (3*wave + 1)*512 + lane*8) = v1;
      *(int4*)(dst + (3*wave + 2)*512 + lane*8) = v2;
      __syncthreads();
      cur ^= 1;
      BH0 = nBH0; BH1 = nBH1; BL0 = nBL0; BL1 = nBL1;
    }
  }

  float* ph = phi + (i*MM + j)*CC*CC;
  const int rbase = (lane >> 4) * 4;
  #pragma unroll
  for (int r = 0; r < 2; ++r) {
    #pragma unroll
    for (int t = 0; t < 4; ++t) {
      const int p = 16*r + rbase + t;
      if (p < CC) {
        #pragma unroll
        for (int s = 0; s < 2; ++s) {
          const int q = 16*s + row;
          if (q < CC) {
            float v = a0*acc[0][r][s][t] + a1*acc[1][r][s][t] + a2*acc[2][r][s][t];
            ph[p*CC + q] = v;
          }
        }
      }
    }
  }
}

// ---------- zero ----------
__global__ void k_zero(float* __restrict__ p, int n) {
  int idx = blockIdx.x*256 + threadIdx.x;
  if (idx < n) p[idx] = 0.f;
}

// ---------- damped LBP update + fused stot (atomics) — R7-verified ----------
__global__ __launch_bounds__(256) void k_up4(const float* __restrict__ phi,
                                             const float* __restrict__ psi,
                                             const float* __restrict__ stot_cur,
                                             float* __restrict__ stot_next,
                                             const float* __restrict__ mb_old,
                                             float* __restrict__ mb_new) {
  const int i  = blockIdx.x / 25;
  const int jg = blockIdx.x % 25;
  const int wave = threadIdx.x >> 6;
  const int lane = threadIdx.x & 63;
  const int j = jg*4 + wave;
  const int half = lane >> 5;
  const int q = lane & 31;

  __shared__ float psi_st[32];
  if (threadIdx.x < CC)
    psi_st[threadIdx.x] = psi[i*CC + threadIdx.x] + stot_cur[i*CC + threadIdx.x];
  __syncthreads();

  float csr = (q < CC) ? psi_st[q] - mb_old[(j*MM + i)*CC + q] : -1e30f;

  const float* ph = phi + (i*MM + j)*CC*CC;
  float mv = -1e30f;
  const int p0 = half * 15;
  #pragma unroll
  for (int pp = 0; pp < 15; ++pp) {
    const int p = p0 + pp;
    float v = (q < CC) ? ph[p*CC + q] : -1e30f;
    float cv = __shfl(csr, p, 64);
    mv = fmaxf(mv, v + cv);
  }
  mv = fmaxf(mv, __shfl_xor(mv, 32, 64));
  float x = (q < CC) ? fmaxf(mv, 0.f) : -1e30f;

  float mx = x;
  #pragma unroll
  for (int off = 16; off; off >>= 1) mx = fmaxf(mx, __shfl_xor(mx, off, 64));
  float e = (q < CC) ? expf(x - mx) : 0.f;
  float se = e;
  #pragma unroll
  for (int off = 16; off; off >>= 1) se += __shfl_xor(se, off, 64);

  if (lane < CC) {
    float sm = e / se;
    float old = mb_old[(i*MM + j)*CC + lane];
    float nv = logf(0.5f*expf(old) + 0.5f*sm);
    mb_new[(i*MM + j)*CC + lane] = nv;
    atomicAdd(stot_next + j*CC + lane, nv);
  }
}

// ---------- out[i,:] = softmax( psi + stot_final[i,:] - mbar[i,i,:] ) ----------
__global__ __launch_bounds__(64) void k_final(const float* __restrict__ psi,
                                              const float* __restrict__ stotN,
                                              const float* __restrict__ mb,
                                              float* __restrict__ out) {
  int i = blockIdx.x;
  int lane = threadIdx.x;
  float x = -1e30f;
  if (lane < CC)
    x = psi[i*CC + lane] + stotN[i*CC + lane] - mb[(i*MM + i)*CC + lane];
  float mx = x;
  #pragma unroll
  for (int off = 16; off; off >>= 1) mx = fmaxf(mx, __shfl_xor(mx, off, 32));
  float e = (lane < CC) ? expf(x - mx) : 0.f;
  float se = e;
  #pragma unroll
  for (int off = 16; off; off >>= 1) se += __shfl_xor(se, off, 32);
  if (lane < CC) out[i*CC + lane] = e / se;
}

extern "C" void kernel_launch(void* const* d_in, const int* in_sizes, int n_in,
                              void* d_out, int out_size, void* d_ws, size_t ws_size,
                              hipStream_t stream) {
  (void)in_sizes; (void)n_in; (void)out_size; (void)ws_size;
  const float* ent  = (const float*)d_in[0];
  const float* fmc  = (const float*)d_in[1];
  const float* W    = (const float*)d_in[2];
  const float* b    = (const float*)d_in[3];
  const float* Bm   = (const float*)d_in[4];
  const float* R    = (const float*)d_in[5];
  const float* Dm   = (const float*)d_in[6];
  float* out = (float*)d_out;
  float* ws  = (float*)d_ws;

  float* f    = ws + 0;
  float* psi  = ws + 60000;
  float* t    = ws + 63000;
  float* a    = ws + 153000;
  short* REH  = (short*)(ws + 183000);
  short* REL  = (short*)(ws + 1719000);
  short* entH = (short*)(ws + 3255000);
  short* entL = (short*)(ws + 3767000);
  float* phi  = ws + 4279000;
  float* mbA  = ws + 13279000;
  float* mbB  = ws + 13579000;
  float* stotbuf = ws + 13879000;   // (NLOOP+1)*3000 floats
  float* gst  = ws + 183000;        // transient g stash (REH area, consumed before k_re2)
  short* RH   = (short*)phi;        // transient R split (phi area, dead before k_phi7)
  short* RL   = RH + NK*320*320;

  k_zero<<<(633000 + 255)/256, 256, 0, stream>>>(mbA, 633000);  // mbA+mbB+stotbuf

  k_f  <<<MM, 320, 0, stream>>>(fmc, W, b, f);
  k_gt <<<1900, 256, 0, stream>>>(Bm, Dm, f, gst, t);
  k_aux<<<3820, 256, 0, stream>>>(ent, f, gst, t, R, psi, a, entH, entL, RH, RL);

  {
    dim3 grid(10, 25, 3);
    k_re2<<<grid, 256, 0, stream>>>(RH, RL, entH, entL, REH, REL);
  }
  k_phi7<<<2500, 256, 0, stream>>>(a, REH, REL, entH, entL, phi);

  float* cur = mbA; float* nxt = mbB;
  for (int it = 0; it < NLOOP; ++it) {
    k_up4<<<MM*25, 256, 0, stream>>>(phi, psi,
                                     stotbuf + it*MM*CC,
                                     stotbuf + (it+1)*MM*CC,
                                     cur, nxt);
    float* tmp = cur; cur = nxt; nxt = tmp;
  }
  k_final<<<MM, 64, 0, stream>>>(psi, stotbuf + NLOOP*MM*CC, cur, out);
}